// Round 1
// baseline (1206.344 us; speedup 1.0000x reference)
//
#include <hip/hip_runtime.h>

// Problem constants
#define NN 16384
// ws (bf16) region offsets, in elements
#define OFF_EWT 0
#define OFF_WQT 4096
#define OFF_WKT 36864
#define OFF_WVT 69632
#define OFF_AFT 102400
#define OFF_W1T 135168
#define OFF_W2T 266240
#define OFF_F2N 397312
#define TOTAL_W 413696

typedef __attribute__((ext_vector_type(8))) short bf16x8;
typedef __attribute__((ext_vector_type(4))) float f32x4;

static __device__ __forceinline__ short f2bf(float f) {
  unsigned u = __builtin_bit_cast(unsigned, f);
  u += 0x7fffu + ((u >> 16) & 1u);           // RNE
  return (short)(u >> 16);
}
static __device__ __forceinline__ float bf2f(short h) {
  unsigned u = ((unsigned)(unsigned short)h) << 16;
  return __builtin_bit_cast(float, u);
}
static __device__ __forceinline__ float gelu_f(float x) {
  float x3 = x * x * x;
  return 0.5f * x * (1.0f + tanhf(0.79788456080286541f * (x + 0.044715f * x3)));
}
static __device__ __forceinline__ f32x4 mfma16(bf16x8 a, bf16x8 b, f32x4 c) {
  return __builtin_amdgcn_mfma_f32_16x16x32_bf16(a, b, c, 0, 0, 0);
}
// swizzled byte offset inside a [R][128]-bf16 LDS tile (XOR bank swizzle)
static __device__ __forceinline__ int swzb(int row, int col) {
  return row * 256 + ((col * 2) ^ ((row & 7) << 4));
}
static __device__ __forceinline__ bf16x8 tile_ld8(const short* base, int row, int col) {
  return *(const bf16x8*)((const char*)base + swzb(row, col));
}
static __device__ __forceinline__ void tile_st16(short* base, int row, int col, short v) {
  *(short*)((char*)base + swzb(row, col)) = v;
}
static __device__ __forceinline__ float tile_ldf(const short* base, int row, int col) {
  return bf2f(*(const short*)((const char*)base + swzb(row, col)));
}
// stage a [128][128] bf16 tile (row stride `stride` elems) from global into swizzled LDS
static __device__ __forceinline__ void stage_w(short* dst, const short* src, int stride, int tid) {
  #pragma unroll
  for (int it = 0; it < 8; ++it) {
    int e = (it * 256 + tid) * 8;
    int row = e >> 7, col = e & 127;
    bf16x8 v = *(const bf16x8*)(src + row * stride + col);
    *(bf16x8*)((char*)dst + swzb(row, col)) = v;
  }
}
// P = A(fA) @ W(lds_w), store bf16 D-layout into dst tile
static __device__ __forceinline__ void proj_store(const bf16x8* fA, const short* ldsw,
                                                  short* dst, int li, int lq) {
  #pragma unroll
  for (int c = 0; c < 8; ++c) {
    f32x4 a = {0.f, 0.f, 0.f, 0.f};
    #pragma unroll
    for (int s = 0; s < 4; ++s) a = mfma16(fA[s], tile_ld8(ldsw, c * 16 + li, s * 32 + lq * 8), a);
    #pragma unroll
    for (int r = 0; r < 4; ++r) tile_st16(dst, lq * 4 + r, c * 16 + li, f2bf(a[r]));
  }
}
static __device__ __forceinline__ void layer_norm(f32x4* a, const float* g, const float* b,
                                                  int li, int lq) {
  float gg[8], bb[8];
  #pragma unroll
  for (int c = 0; c < 8; ++c) { gg[c] = g[c * 16 + li]; bb[c] = b[c * 16 + li]; }
  #pragma unroll
  for (int r = 0; r < 4; ++r) {
    float s1 = 0.f, s2 = 0.f;
    #pragma unroll
    for (int c = 0; c < 8; ++c) { float v = a[c][r]; s1 += v; s2 += v * v; }
    #pragma unroll
    for (int m = 1; m <= 8; m <<= 1) { s1 += __shfl_xor(s1, m, 64); s2 += __shfl_xor(s2, m, 64); }
    float mean = s1 * (1.f / 128.f);
    float var = s2 * (1.f / 128.f) - mean * mean;
    float rstd = rsqrtf(var + 1e-5f);
    #pragma unroll
    for (int c = 0; c < 8; ++c) a[c][r] = (a[c][r] - mean) * rstd * gg[c] + bb[c];
  }
}

// ---- prep: transpose + fp32->bf16 all weight matrices into ws ----
__global__ void prep_kernel(const float* __restrict__ ew, const float* __restrict__ wq,
                            const float* __restrict__ wk, const float* __restrict__ wv,
                            const float* __restrict__ afc, const float* __restrict__ w1,
                            const float* __restrict__ w2, const float* __restrict__ f2n,
                            short* __restrict__ wsb) {
  int tt = blockIdx.x * 256 + threadIdx.x;
  if (tt >= TOTAL_W) return;
  short v;
  if (tt < OFF_WQT) {                       // EWT [128][32] <- ew [32][128]
    int u = tt; int row = u >> 5, colr = u & 31;
    v = f2bf(ew[colr * 128 + row]);
  } else if (tt < OFF_WKT) {                // WQT [2][128][128]
    int u = tt - OFF_WQT; int i = u >> 14; u &= 16383; int row = u >> 7, colr = u & 127;
    v = f2bf(wq[i * 16384 + colr * 128 + row]);
  } else if (tt < OFF_WVT) {
    int u = tt - OFF_WKT; int i = u >> 14; u &= 16383; int row = u >> 7, colr = u & 127;
    v = f2bf(wk[i * 16384 + colr * 128 + row]);
  } else if (tt < OFF_AFT) {
    int u = tt - OFF_WVT; int i = u >> 14; u &= 16383; int row = u >> 7, colr = u & 127;
    v = f2bf(wv[i * 16384 + colr * 128 + row]);
  } else if (tt < OFF_W1T) {                // AFT [2][128][128] <- afc [2][128][128] (in,out)
    int u = tt - OFF_AFT; int i = u >> 14; u &= 16383; int row = u >> 7, colr = u & 127;
    v = f2bf(afc[i * 16384 + colr * 128 + row]);
  } else if (tt < OFF_W2T) {                // W1T [2][512][128] <- w1 [2][128][512]
    int u = tt - OFF_W1T; int i = u >> 16; u &= 65535; int row = u >> 7, colr = u & 127;
    v = f2bf(w1[i * 65536 + colr * 512 + row]);
  } else if (tt < OFF_F2N) {                // W2T [2][128][512] <- w2 [2][512][128]
    int u = tt - OFF_W2T; int i = u >> 16; u &= 65535; int row = u >> 9, colr = u & 511;
    v = f2bf(w2[i * 65536 + colr * 128 + row]);
  } else {                                  // F2N [128][128] <- f2n [128][128]
    int u = tt - OFF_F2N; int row = u >> 7, colr = u & 127;
    v = f2bf(f2n[colr * 128 + row]);
  }
  wsb[tt] = v;
}

// ---- fused main kernel: 1 wave = 1 node, 4 waves/WG ----
__global__ __launch_bounds__(256, 2) void fused_kernel(
    const float* __restrict__ node_h, const int* __restrict__ src_idx,
    const float* __restrict__ edge_feat, const float* __restrict__ t_arr,
    const float* __restrict__ t_now, const float* __restrict__ edge_fc_b,
    const float* __restrict__ basis_freq, const float* __restrict__ phase,
    const float* __restrict__ attn_fc_b, const float* __restrict__ attn_ln_g,
    const float* __restrict__ attn_ln_b, const float* __restrict__ ffn_b1,
    const float* __restrict__ ffn_b2, const float* __restrict__ ffn_ln_g,
    const float* __restrict__ ffn_ln_b, const float* __restrict__ f2n_b,
    const float* __restrict__ fin_g, const float* __restrict__ fin_b,
    const short* __restrict__ wsb, float* __restrict__ out) {
  __shared__ __align__(16) short lds_w[16384];     // 32KB weight stage (+ per-node Vt during attn)
  __shared__ __align__(16) short lds_f[4][2048];   // per-node f [16][128] bf16 (swizzled)
  __shared__ __align__(16) short lds_qk[4][4096];  // per-node Q,K tiles / scratch

  const int tid = (int)threadIdx.x;
  const int w = tid >> 6, lane = tid & 63, li = lane & 15, lq = lane >> 4;
  const int n = (int)blockIdx.x * 4 + w;
  short* myf = lds_f[w];
  short* myQ = lds_qk[w];
  short* myK = lds_qk[w] + 2048;
  short* myVt = lds_w + w * 2048;                  // [128][16] bf16, valid only during attention
  const f32x4 F0 = {0.f, 0.f, 0.f, 0.f};
  const bf16x8 B0 = {0, 0, 0, 0, 0, 0, 0, 0};

  const float tnow = t_now[0];

  f32x4 acc[8];
  // ================= message phase =================
  {
    bf16x8 ea;
    const float* ef = edge_feat + ((size_t)(n * 16 + li)) * 32 + lq * 8;
    #pragma unroll
    for (int j = 0; j < 8; ++j) ea[j] = f2bf(ef[j]);
    const short* ewt = wsb + OFF_EWT;
    #pragma unroll
    for (int c = 0; c < 8; ++c) {
      bf16x8 eb = *(const bf16x8*)(ewt + (c * 16 + li) * 32 + lq * 8);
      acc[c] = mfma16(ea, eb, F0);
    }
  }
  {
    float bfq[8], phs[8], ebs[8];
    #pragma unroll
    for (int c = 0; c < 8; ++c) {
      int col = c * 16 + li;
      bfq[c] = basis_freq[col]; phs[c] = phase[col]; ebs[c] = edge_fc_b[col];
    }
    #pragma unroll
    for (int r = 0; r < 4; ++r) {
      int m = lq * 4 + r;
      int sidx = src_idx[n * 16 + m];
      float dt = tnow - t_arr[n * 16 + m];
      const float* nh = node_h + (size_t)sidx * 128;
      #pragma unroll
      for (int c = 0; c < 8; ++c) {
        int col = c * 16 + li;
        float x = gelu_f(acc[c][r] + ebs[c]);
        x += nh[col];
        x += __cosf(dt * bfq[c] + phs[c]);
        acc[c][r] = x;
      }
    }
  }
  #pragma unroll
  for (int r = 0; r < 4; ++r)
    #pragma unroll
    for (int c = 0; c < 8; ++c)
      tile_st16(myf, lq * 4 + r, c * 16 + li, f2bf(acc[c][r]));

  bf16x8 fA[4];

  // ================= transformer layers =================
  for (int il = 0; il < 2; ++il) {
    const short* WQT = wsb + OFF_WQT + il * 16384;
    const short* WKT = wsb + OFF_WKT + il * 16384;
    const short* WVT = wsb + OFF_WVT + il * 16384;
    const short* AFT = wsb + OFF_AFT + il * 16384;
    const short* W1T = wsb + OFF_W1T + il * 65536;
    const short* W2T = wsb + OFF_W2T + il * 65536;

    // ---- Q ----
    __syncthreads();
    stage_w(lds_w, WQT, 128, tid);
    __syncthreads();
    #pragma unroll
    for (int s = 0; s < 4; ++s) fA[s] = tile_ld8(myf, li, s * 32 + lq * 8);
    proj_store(fA, lds_w, myQ, li, lq);
    // ---- K ----
    __syncthreads();
    stage_w(lds_w, WKT, 128, tid);
    __syncthreads();
    proj_store(fA, lds_w, myK, li, lq);
    // ---- V ----
    __syncthreads();
    stage_w(lds_w, WVT, 128, tid);
    __syncthreads();
    f32x4 vacc[8];
    #pragma unroll
    for (int c = 0; c < 8; ++c) {
      f32x4 a = F0;
      #pragma unroll
      for (int s = 0; s < 4; ++s) a = mfma16(fA[s], tile_ld8(lds_w, c * 16 + li, s * 32 + lq * 8), a);
      vacc[c] = a;
    }
    __syncthreads();  // all waves done reading WVT before Vt overwrites lds_w
    #pragma unroll
    for (int c = 0; c < 8; ++c)
      #pragma unroll
      for (int r = 0; r < 4; ++r)
        myVt[(c * 16 + li) * 16 + (lq * 4 + r)] = f2bf(vacc[c][r]);  // Vt[dv][k]

    // ---- attention (wave-local) ----
    f32x4 oacc[8];
    #pragma unroll
    for (int h = 0; h < 8; ++h) {
      bf16x8 ka = B0, qa = B0;
      if (lq < 2) {
        ka = tile_ld8(myK, li, h * 16 + lq * 8);
        qa = tile_ld8(myQ, li, h * 16 + lq * 8);
      }
      f32x4 st = mfma16(ka, qa, F0);  // S^T: row k=lq*4+r, col q=li
      float p[4]; float mx = -1e30f;
      #pragma unroll
      for (int r = 0; r < 4; ++r) { p[r] = st[r] * 0.25f; mx = fmaxf(mx, p[r]); }
      mx = fmaxf(mx, __shfl_xor(mx, 16, 64));
      mx = fmaxf(mx, __shfl_xor(mx, 32, 64));
      float sum = 0.f;
      #pragma unroll
      for (int r = 0; r < 4; ++r) { p[r] = __expf(p[r] - mx); sum += p[r]; }
      sum += __shfl_xor(sum, 16, 64);
      sum += __shfl_xor(sum, 32, 64);
      float inv = 1.0f / sum;
      #pragma unroll
      for (int r = 0; r < 4; ++r) p[r] *= inv;
      // redistribute P^T(D-layout) -> A-frag of P for K=32 MFMA (k>=16 zero)
      bf16x8 pa;
      #pragma unroll
      for (int j = 0; j < 8; ++j) {
        float v = __shfl(p[j & 3], li + 16 * (2 * lq + (j >> 2)), 64);
        pa[j] = (lq < 2) ? f2bf(v) : (short)0;
      }
      bf16x8 vb = B0;
      if (lq < 2) vb = *(const bf16x8*)(myVt + (h * 16 + li) * 16 + lq * 8);
      oacc[h] = mfma16(pa, vb, F0);  // O: row q=lq*4+r, col dv=li (head h)
    }

    // ---- attn_fc + residual + LN ----
    __syncthreads();
    stage_w(lds_w, AFT, 128, tid);
    __syncthreads();
    #pragma unroll
    for (int h = 0; h < 8; ++h)
      #pragma unroll
      for (int r = 0; r < 4; ++r)
        tile_st16(myQ, lq * 4 + r, h * 16 + li, f2bf(oacc[h][r]));  // O -> scratch for transpose
    bf16x8 oa[4];
    #pragma unroll
    for (int s = 0; s < 4; ++s) oa[s] = tile_ld8(myQ, li, s * 32 + lq * 8);
    #pragma unroll
    for (int c = 0; c < 8; ++c) {
      f32x4 a = F0;
      #pragma unroll
      for (int s = 0; s < 4; ++s) a = mfma16(oa[s], tile_ld8(lds_w, c * 16 + li, s * 32 + lq * 8), a);
      float bias = attn_fc_b[il * 128 + c * 16 + li];
      #pragma unroll
      for (int r = 0; r < 4; ++r)
        acc[c][r] = a[r] + bias + tile_ldf(myf, lq * 4 + r, c * 16 + li);
    }
    layer_norm(acc, attn_ln_g + il * 128, attn_ln_b + il * 128, li, lq);
    #pragma unroll
    for (int r = 0; r < 4; ++r)
      #pragma unroll
      for (int c = 0; c < 8; ++c)
        tile_st16(myf, lq * 4 + r, c * 16 + li, f2bf(acc[c][r]));
    #pragma unroll
    for (int s = 0; s < 4; ++s) fA[s] = tile_ld8(myf, li, s * 32 + lq * 8);

    // ---- FFN (fused w1+relu+w2 over 4 col-tiles) ----
    f32x4 facc[8];
    #pragma unroll
    for (int c = 0; c < 8; ++c) facc[c] = F0;
    for (int ct = 0; ct < 4; ++ct) {
      __syncthreads();
      stage_w(lds_w, W1T + ct * 16384, 128, tid);
      __syncthreads();
      f32x4 hacc[8];
      #pragma unroll
      for (int c = 0; c < 8; ++c) {
        f32x4 a = F0;
        #pragma unroll
        for (int s = 0; s < 4; ++s) a = mfma16(fA[s], tile_ld8(lds_w, c * 16 + li, s * 32 + lq * 8), a);
        float b1 = ffn_b1[il * 512 + ct * 128 + c * 16 + li];
        #pragma unroll
        for (int r = 0; r < 4; ++r) a[r] = fmaxf(a[r] + b1, 0.f);
        hacc[c] = a;
      }
      #pragma unroll
      for (int r = 0; r < 4; ++r)
        #pragma unroll
        for (int c = 0; c < 8; ++c)
          tile_st16(myQ, lq * 4 + r, c * 16 + li, f2bf(hacc[c][r]));
      bf16x8 ha[4];
      #pragma unroll
      for (int s = 0; s < 4; ++s) ha[s] = tile_ld8(myQ, li, s * 32 + lq * 8);
      __syncthreads();
      stage_w(lds_w, W2T + ct * 128, 512, tid);
      __syncthreads();
      #pragma unroll
      for (int c = 0; c < 8; ++c) {
        f32x4 a = facc[c];
        #pragma unroll
        for (int s = 0; s < 4; ++s) a = mfma16(ha[s], tile_ld8(lds_w, c * 16 + li, s * 32 + lq * 8), a);
        facc[c] = a;
      }
    }
    #pragma unroll
    for (int c = 0; c < 8; ++c) {
      float b2 = ffn_b2[il * 128 + c * 16 + li];
      #pragma unroll
      for (int r = 0; r < 4; ++r)
        facc[c][r] += b2 + tile_ldf(myf, lq * 4 + r, c * 16 + li);
    }
    layer_norm(facc, ffn_ln_g + il * 128, ffn_ln_b + il * 128, li, lq);
    #pragma unroll
    for (int r = 0; r < 4; ++r)
      #pragma unroll
      for (int c = 0; c < 8; ++c)
        tile_st16(myf, lq * 4 + r, c * 16 + li, f2bf(facc[c][r]));
    #pragma unroll
    for (int c = 0; c < 8; ++c) acc[c] = facc[c];  // keep post-LN f for pooling
  }

  // ================= pooling + fea2node + final LN =================
  float pc[8];
  #pragma unroll
  for (int c = 0; c < 8; ++c) {
    float s = acc[c][0] + acc[c][1] + acc[c][2] + acc[c][3];
    s += __shfl_xor(s, 16, 64);
    s += __shfl_xor(s, 32, 64);
    pc[c] = s * (1.f / 16.f);
  }
  float* ps = (float*)myQ;  // 128 floats scratch
  if (lq == 0) {
    #pragma unroll
    for (int c = 0; c < 8; ++c) ps[c * 16 + li] = pc[c];
  }
  const short* F2NT = wsb + OFF_F2N;
  float yv[2];
  #pragma unroll
  for (int half = 0; half < 2; ++half) {
    int col = half * 64 + lane;
    float dot = 0.f;
    for (int d0 = 0; d0 < 128; d0 += 8) {
      bf16x8 wv8 = *(const bf16x8*)(F2NT + col * 128 + d0);
      f32x4 p0 = *(const f32x4*)(ps + d0);
      f32x4 p1 = *(const f32x4*)(ps + d0 + 4);
      dot += p0[0] * bf2f(wv8[0]) + p0[1] * bf2f(wv8[1]) + p0[2] * bf2f(wv8[2]) + p0[3] * bf2f(wv8[3]);
      dot += p1[0] * bf2f(wv8[4]) + p1[1] * bf2f(wv8[5]) + p1[2] * bf2f(wv8[6]) + p1[3] * bf2f(wv8[7]);
    }
    yv[half] = gelu_f(dot + f2n_b[col]) + node_h[(size_t)n * 128 + col];
  }
  float s1 = yv[0] + yv[1], s2 = yv[0] * yv[0] + yv[1] * yv[1];
  #pragma unroll
  for (int m = 1; m <= 32; m <<= 1) { s1 += __shfl_xor(s1, m, 64); s2 += __shfl_xor(s2, m, 64); }
  float mean = s1 * (1.f / 128.f);
  float var = s2 * (1.f / 128.f) - mean * mean;
  float rstd = rsqrtf(var + 1e-5f);
  #pragma unroll
  for (int half = 0; half < 2; ++half) {
    int col = half * 64 + lane;
    out[(size_t)n * 128 + col] = (yv[half] - mean) * rstd * fin_g[col] + fin_b[col];
  }
}

extern "C" void kernel_launch(void* const* d_in, const int* in_sizes, int n_in,
                              void* d_out, int out_size, void* d_ws, size_t ws_size,
                              hipStream_t stream) {
  const float* node_h    = (const float*)d_in[0];
  const int*   src_idx   = (const int*)d_in[1];
  const float* edge_feat = (const float*)d_in[2];
  const float* t_arr     = (const float*)d_in[3];
  const float* t_now     = (const float*)d_in[4];
  const float* edge_fc_w = (const float*)d_in[5];
  const float* edge_fc_b = (const float*)d_in[6];
  const float* basis_frq = (const float*)d_in[7];
  const float* phase     = (const float*)d_in[8];
  const float* wq        = (const float*)d_in[9];
  const float* wk        = (const float*)d_in[10];
  const float* wv        = (const float*)d_in[11];
  const float* attn_fc_w = (const float*)d_in[12];
  const float* attn_fc_b = (const float*)d_in[13];
  const float* attn_ln_g = (const float*)d_in[14];
  const float* attn_ln_b = (const float*)d_in[15];
  const float* ffn_w1    = (const float*)d_in[16];
  const float* ffn_b1    = (const float*)d_in[17];
  const float* ffn_w2    = (const float*)d_in[18];
  const float* ffn_b2    = (const float*)d_in[19];
  const float* ffn_ln_g  = (const float*)d_in[20];
  const float* ffn_ln_b  = (const float*)d_in[21];
  const float* f2n_w     = (const float*)d_in[22];
  const float* f2n_b     = (const float*)d_in[23];
  const float* fin_g     = (const float*)d_in[24];
  const float* fin_b     = (const float*)d_in[25];
  short* wsb = (short*)d_ws;

  prep_kernel<<<(TOTAL_W + 255) / 256, 256, 0, stream>>>(
      edge_fc_w, wq, wk, wv, attn_fc_w, ffn_w1, ffn_w2, f2n_w, wsb);
  fused_kernel<<<NN / 4, 256, 0, stream>>>(
      node_h, src_idx, edge_feat, t_arr, t_now, edge_fc_b, basis_frq, phase,
      attn_fc_b, attn_ln_g, attn_ln_b, ffn_b1, ffn_b2, ffn_ln_g, ffn_ln_b,
      f2n_b, fin_g, fin_b, wsb, (float*)d_out);
}

// Round 2
// 824.794 us; speedup vs baseline: 1.4626x; 1.4626x over previous
//
#include <hip/hip_runtime.h>

// Problem constants
#define NN 16384
// ws (bf16) region offsets, in elements
#define OFF_EWT 0
#define OFF_WQT 4096
#define OFF_WKT 36864
#define OFF_WVT 69632
#define OFF_AFT 102400
#define OFF_W1T 135168
#define OFF_W2T 266240
#define OFF_F2N 397312
#define TOTAL_W 413696

typedef __attribute__((ext_vector_type(8))) short bf16x8;
typedef __attribute__((ext_vector_type(4))) short bf16x4;
typedef __attribute__((ext_vector_type(4))) float f32x4;

static __device__ __forceinline__ short f2bf(float f) {
  unsigned u = __builtin_bit_cast(unsigned, f);
  u += 0x7fffu + ((u >> 16) & 1u);           // RNE
  return (short)(u >> 16);
}
static __device__ __forceinline__ float bf2f(short h) {
  unsigned u = ((unsigned)(unsigned short)h) << 16;
  return __builtin_bit_cast(float, u);
}
static __device__ __forceinline__ float gelu_f(float x) {
  // 0.5x(1+tanh(0.79788456*(x+0.044715x^3))) == x - x/(exp(2k)+1)
  float e = __expf(1.5957691216057308f * (x + 0.044715f * x * x * x));
  return x - x / (e + 1.0f);
}
static __device__ __forceinline__ f32x4 mfma16(bf16x8 a, bf16x8 b, f32x4 c) {
  return __builtin_amdgcn_mfma_f32_16x16x32_bf16(a, b, c, 0, 0, 0);
}
// swizzled byte offset inside a [R][128]-bf16 LDS tile (XOR bank swizzle)
static __device__ __forceinline__ int swzb(int row, int col) {
  return row * 256 + ((col * 2) ^ ((row & 7) << 4));
}
static __device__ __forceinline__ bf16x8 tile_ld8(const short* base, int row, int col) {
  return *(const bf16x8*)((const char*)base + swzb(row, col));
}
static __device__ __forceinline__ void tile_st16(short* base, int row, int col, short v) {
  *(short*)((char*)base + swzb(row, col)) = v;
}
// async stage: [128][stride] global (row-major) -> 32KB swizzled LDS tile.
// LDS dest linear (wave-uniform base + lane*16); global source pre-swizzled.
static __device__ __forceinline__ void stage_async(short* dst, const short* src, int stride,
                                                   int w, int lane) {
  #pragma unroll
  for (int it = 0; it < 8; ++it) {
    int dbase = (it * 4 + w) * 1024;          // wave-uniform dest byte offset
    int d = dbase + lane * 16;
    int row = d >> 8;
    int scolb = (d & 255) ^ ((row & 7) << 4); // source byte-in-row (involution)
    const short* sp = src + row * stride + (scolb >> 1);
    __builtin_amdgcn_global_load_lds(
        (const __attribute__((address_space(1))) unsigned int*)sp,
        (__attribute__((address_space(3))) unsigned int*)((char*)dst + dbase),
        16, 0, 0);
  }
}

#define LD_FA(SRC)                                                        \
  _Pragma("unroll") for (int _s = 0; _s < 4; ++_s)                        \
      fA[_s] = tile_ld8((SRC), li, _s * 32 + lq * 8);

#define ST_TILE(T, ACC)                                                   \
  _Pragma("unroll") for (int _c = 0; _c < 8; ++_c)                        \
    _Pragma("unroll") for (int _r = 0; _r < 4; ++_r)                      \
      tile_st16((T), lq * 4 + _r, _c * 16 + li, f2bf((ACC)[_c][_r]));

#define LAYER_NORM(A, GP, BP) do {                                        \
    float _gg[8], _bb[8];                                                 \
    _Pragma("unroll") for (int _c = 0; _c < 8; ++_c) {                    \
      _gg[_c] = (GP)[_c * 16 + li]; _bb[_c] = (BP)[_c * 16 + li]; }       \
    _Pragma("unroll") for (int _r = 0; _r < 4; ++_r) {                    \
      float _s1 = 0.f, _s2 = 0.f;                                         \
      _Pragma("unroll") for (int _c = 0; _c < 8; ++_c) {                  \
        float _v = (A)[_c][_r]; _s1 += _v; _s2 += _v * _v; }              \
      _Pragma("unroll") for (int _m = 1; _m <= 8; _m <<= 1) {             \
        _s1 += __shfl_xor(_s1, _m, 64); _s2 += __shfl_xor(_s2, _m, 64); } \
      float _mean = _s1 * (1.f / 128.f);                                  \
      float _var = _s2 * (1.f / 128.f) - _mean * _mean;                   \
      float _rstd = rsqrtf(_var + 1e-5f);                                 \
      _Pragma("unroll") for (int _c = 0; _c < 8; ++_c)                    \
        (A)[_c][_r] = ((A)[_c][_r] - _mean) * _rstd * _gg[_c] + _bb[_c];  \
    }                                                                     \
  } while (0)

// ---- prep: transpose + fp32->bf16 all weight matrices into ws ----
__global__ void prep_kernel(const float* __restrict__ ew, const float* __restrict__ wq,
                            const float* __restrict__ wk, const float* __restrict__ wv,
                            const float* __restrict__ afc, const float* __restrict__ w1,
                            const float* __restrict__ w2, const float* __restrict__ f2n,
                            short* __restrict__ wsb) {
  int tt = blockIdx.x * 256 + threadIdx.x;
  if (tt >= TOTAL_W) return;
  short v;
  if (tt < OFF_WQT) {                       // EWT [128][32] <- ew [32][128]
    int u = tt; int row = u >> 5, colr = u & 31;
    v = f2bf(ew[colr * 128 + row]);
  } else if (tt < OFF_WKT) {                // WQT [2][128][128]
    int u = tt - OFF_WQT; int i = u >> 14; u &= 16383; int row = u >> 7, colr = u & 127;
    v = f2bf(wq[i * 16384 + colr * 128 + row]);
  } else if (tt < OFF_WVT) {
    int u = tt - OFF_WKT; int i = u >> 14; u &= 16383; int row = u >> 7, colr = u & 127;
    v = f2bf(wk[i * 16384 + colr * 128 + row]);
  } else if (tt < OFF_AFT) {
    int u = tt - OFF_WVT; int i = u >> 14; u &= 16383; int row = u >> 7, colr = u & 127;
    v = f2bf(wv[i * 16384 + colr * 128 + row]);
  } else if (tt < OFF_W1T) {                // AFT [2][128][128]
    int u = tt - OFF_AFT; int i = u >> 14; u &= 16383; int row = u >> 7, colr = u & 127;
    v = f2bf(afc[i * 16384 + colr * 128 + row]);
  } else if (tt < OFF_W2T) {                // W1T [2][512][128] <- w1 [2][128][512]
    int u = tt - OFF_W1T; int i = u >> 16; u &= 65535; int row = u >> 7, colr = u & 127;
    v = f2bf(w1[i * 65536 + colr * 512 + row]);
  } else if (tt < OFF_F2N) {                // W2T [2][128][512] <- w2 [2][512][128]
    int u = tt - OFF_W2T; int i = u >> 16; u &= 65535; int row = u >> 9, colr = u & 511;
    v = f2bf(w2[i * 65536 + colr * 128 + row]);
  } else {                                  // F2N [128][128] <- f2n [128][128]
    int u = tt - OFF_F2N; int row = u >> 7, colr = u & 127;
    v = f2bf(f2n[colr * 128 + row]);
  }
  wsb[tt] = v;
}

// ---- fused main kernel: 1 wave = 1 node, 4 waves/WG ----
__global__ __launch_bounds__(256, 2) void fused_kernel(
    const float* __restrict__ node_h, const int* __restrict__ src_idx,
    const float* __restrict__ edge_feat, const float* __restrict__ t_arr,
    const float* __restrict__ t_now, const float* __restrict__ edge_fc_b,
    const float* __restrict__ basis_freq, const float* __restrict__ phase,
    const float* __restrict__ attn_fc_b, const float* __restrict__ attn_ln_g,
    const float* __restrict__ attn_ln_b, const float* __restrict__ ffn_b1,
    const float* __restrict__ ffn_b2, const float* __restrict__ ffn_ln_g,
    const float* __restrict__ ffn_ln_b, const float* __restrict__ f2n_b,
    const float* __restrict__ fin_g, const float* __restrict__ fin_b,
    const short* __restrict__ wsb, float* __restrict__ out) {
  __shared__ __align__(16) short lds_w[16384];     // 32KB weight stage (+ per-node Vt during attn)
  __shared__ __align__(16) short lds_f[4][2048];   // per-node f [16][128] bf16 (swizzled)
  __shared__ __align__(16) short lds_qk[4][4096];  // per-node Q,K tiles / scratch

  const int tid = (int)threadIdx.x;
  const int w = tid >> 6, lane = tid & 63, li = lane & 15, lq = lane >> 4;
  const int n = (int)blockIdx.x * 4 + w;
  short* myf = lds_f[w];
  short* myQ = lds_qk[w];
  short* myK = lds_qk[w] + 2048;
  short* myVt = lds_w + w * 2048;                  // [128][16] bf16, valid only during attention
  const f32x4 F0 = {0.f, 0.f, 0.f, 0.f};
  const bf16x8 B0 = {0, 0, 0, 0, 0, 0, 0, 0};

  const float tnow = t_now[0];

  f32x4 acc[8];
  // ================= message phase =================
  {
    const float* ef = edge_feat + ((size_t)(n * 16 + li)) * 32 + lq * 8;
    f32x4 e0 = *(const f32x4*)(ef);
    f32x4 e1 = *(const f32x4*)(ef + 4);
    bf16x8 ea;
    #pragma unroll
    for (int j = 0; j < 4; ++j) { ea[j] = f2bf(e0[j]); ea[j + 4] = f2bf(e1[j]); }
    const short* ewt = wsb + OFF_EWT;
    #pragma unroll
    for (int c = 0; c < 8; ++c) {
      bf16x8 eb = *(const bf16x8*)(ewt + (c * 16 + li) * 32 + lq * 8);
      acc[c] = mfma16(ea, eb, F0);
    }
  }
  {
    float bfq[8], phs[8], ebs[8];
    #pragma unroll
    for (int c = 0; c < 8; ++c) {
      int col = c * 16 + li;
      bfq[c] = basis_freq[col]; phs[c] = phase[col]; ebs[c] = edge_fc_b[col];
    }
    #pragma unroll
    for (int r = 0; r < 4; ++r) {
      int m = lq * 4 + r;
      int sidx = src_idx[n * 16 + m];
      float dt = tnow - t_arr[n * 16 + m];
      const float* nh = node_h + (size_t)sidx * 128;
      #pragma unroll
      for (int c = 0; c < 8; ++c) {
        int col = c * 16 + li;
        float x = gelu_f(acc[c][r] + ebs[c]);
        x += nh[col];
        x += __cosf(dt * bfq[c] + phs[c]);
        acc[c][r] = x;
      }
    }
  }
  ST_TILE(myf, acc);

  bf16x8 fA[4];

  // ================= transformer layers =================
  for (int il = 0; il < 2; ++il) {
    const short* WQT = wsb + OFF_WQT + il * 16384;
    const short* WKT = wsb + OFF_WKT + il * 16384;
    const short* WVT = wsb + OFF_WVT + il * 16384;
    const short* AFT = wsb + OFF_AFT + il * 16384;
    const short* W1T = wsb + OFF_W1T + il * 65536;
    const short* W2T = wsb + OFF_W2T + il * 65536;

    // ---- Q ----
    __syncthreads();
    stage_async(lds_w, WQT, 128, w, lane);
    __syncthreads();
    LD_FA(myf);
    {
      f32x4 qacc[8];
      #pragma unroll
      for (int _c = 0; _c < 8; ++_c) {
        f32x4 a = F0;
        #pragma unroll
        for (int _s = 0; _s < 4; ++_s)
          a = mfma16(fA[_s], tile_ld8(lds_w, _c * 16 + li, _s * 32 + lq * 8), a);
        qacc[_c] = a;
      }
      ST_TILE(myQ, qacc);
    }
    // ---- K ----
    __syncthreads();
    stage_async(lds_w, WKT, 128, w, lane);
    __syncthreads();
    {
      f32x4 kacc[8];
      #pragma unroll
      for (int _c = 0; _c < 8; ++_c) {
        f32x4 a = F0;
        #pragma unroll
        for (int _s = 0; _s < 4; ++_s)
          a = mfma16(fA[_s], tile_ld8(lds_w, _c * 16 + li, _s * 32 + lq * 8), a);
        kacc[_c] = a;
      }
      ST_TILE(myK, kacc);
    }
    // ---- V ----
    __syncthreads();
    stage_async(lds_w, WVT, 128, w, lane);
    __syncthreads();
    f32x4 vacc[8];
    #pragma unroll
    for (int _c = 0; _c < 8; ++_c) {
      f32x4 a = F0;
      #pragma unroll
      for (int _s = 0; _s < 4; ++_s)
        a = mfma16(fA[_s], tile_ld8(lds_w, _c * 16 + li, _s * 32 + lq * 8), a);
      vacc[_c] = a;
    }
    __syncthreads();  // all waves done reading WVT before Vt overwrites lds_w
    #pragma unroll
    for (int c = 0; c < 8; ++c) {
      bf16x4 pk;
      #pragma unroll
      for (int r = 0; r < 4; ++r) pk[r] = f2bf(vacc[c][r]);
      *(bf16x4*)(myVt + (c * 16 + li) * 16 + lq * 4) = pk;  // Vt[dv][k], b64 packed
    }

    // ---- attention (wave-local) ----
    f32x4 oacc[8];
    #pragma unroll
    for (int h = 0; h < 8; ++h) {
      bf16x8 ka = B0, qa = B0;
      if (lq < 2) {
        ka = tile_ld8(myK, li, h * 16 + lq * 8);
        qa = tile_ld8(myQ, li, h * 16 + lq * 8);
      }
      f32x4 st = mfma16(ka, qa, F0);  // S^T: row k=lq*4+r, col q=li
      float p[4]; float mx = -1e30f;
      #pragma unroll
      for (int r = 0; r < 4; ++r) { p[r] = st[r] * 0.25f; mx = fmaxf(mx, p[r]); }
      mx = fmaxf(mx, __shfl_xor(mx, 16, 64));
      mx = fmaxf(mx, __shfl_xor(mx, 32, 64));
      float sum = 0.f;
      #pragma unroll
      for (int r = 0; r < 4; ++r) { p[r] = __expf(p[r] - mx); sum += p[r]; }
      sum += __shfl_xor(sum, 16, 64);
      sum += __shfl_xor(sum, 32, 64);
      float inv = 1.0f / sum;
      #pragma unroll
      for (int r = 0; r < 4; ++r) p[r] *= inv;
      // redistribute P^T(D-layout) -> A-frag of P for K=32 MFMA (k>=16 zero)
      bf16x8 pa;
      #pragma unroll
      for (int j = 0; j < 8; ++j) {
        float v = __shfl(p[j & 3], li + 16 * (2 * lq + (j >> 2)), 64);
        pa[j] = (lq < 2) ? f2bf(v) : (short)0;
      }
      bf16x8 vb = B0;
      if (lq < 2) vb = *(const bf16x8*)(myVt + (h * 16 + li) * 16 + lq * 8);
      oacc[h] = mfma16(pa, vb, F0);  // O: row q=lq*4+r, col dv=li (head h)
    }

    // ---- attn_fc + residual + LN ----
    __syncthreads();
    stage_async(lds_w, AFT, 128, w, lane);
    __syncthreads();
    ST_TILE(myQ, oacc);              // O -> scratch for transpose
    bf16x8 oa[4];
    #pragma unroll
    for (int _s = 0; _s < 4; ++_s) oa[_s] = tile_ld8(myQ, li, _s * 32 + lq * 8);
    #pragma unroll
    for (int _c = 0; _c < 8; ++_c) {
      f32x4 a = F0;
      #pragma unroll
      for (int _s = 0; _s < 4; ++_s)
        a = mfma16(oa[_s], tile_ld8(lds_w, _c * 16 + li, _s * 32 + lq * 8), a);
      float bias = attn_fc_b[il * 128 + _c * 16 + li];
      #pragma unroll
      for (int _r = 0; _r < 4; ++_r)
        acc[_c][_r] += a[_r] + bias;   // residual f already in acc (D-layout)
    }
    LAYER_NORM(acc, attn_ln_g + il * 128, attn_ln_b + il * 128);
    ST_TILE(myf, acc);
    LD_FA(myf);

    // ---- FFN (fused w1+relu+w2 over 4 col-tiles) ----
    f32x4 facc[8];
    #pragma unroll
    for (int c = 0; c < 8; ++c) facc[c] = F0;
    for (int ct = 0; ct < 4; ++ct) {
      __syncthreads();
      stage_async(lds_w, W1T + ct * 16384, 128, w, lane);
      __syncthreads();
      {
        f32x4 hacc[8];
        #pragma unroll
        for (int _c = 0; _c < 8; ++_c) {
          f32x4 a = F0;
          #pragma unroll
          for (int _s = 0; _s < 4; ++_s)
            a = mfma16(fA[_s], tile_ld8(lds_w, _c * 16 + li, _s * 32 + lq * 8), a);
          float b1 = ffn_b1[il * 512 + ct * 128 + _c * 16 + li];
          #pragma unroll
          for (int _r = 0; _r < 4; ++_r) a[_r] = fmaxf(a[_r] + b1, 0.f);
          hacc[_c] = a;
        }
        ST_TILE(myQ, hacc);
      }
      bf16x8 ha[4];
      #pragma unroll
      for (int _s = 0; _s < 4; ++_s) ha[_s] = tile_ld8(myQ, li, _s * 32 + lq * 8);
      __syncthreads();
      stage_async(lds_w, W2T + ct * 128, 512, w, lane);
      __syncthreads();
      #pragma unroll
      for (int _c = 0; _c < 8; ++_c) {
        f32x4 a = facc[_c];
        #pragma unroll
        for (int _s = 0; _s < 4; ++_s)
          a = mfma16(ha[_s], tile_ld8(lds_w, _c * 16 + li, _s * 32 + lq * 8), a);
        facc[_c] = a;
      }
    }
    #pragma unroll
    for (int _c = 0; _c < 8; ++_c) {
      float b2 = ffn_b2[il * 128 + _c * 16 + li];
      #pragma unroll
      for (int _r = 0; _r < 4; ++_r)
        facc[_c][_r] += b2 + acc[_c][_r];   // residual from regs
    }
    LAYER_NORM(facc, ffn_ln_g + il * 128, ffn_ln_b + il * 128);
    ST_TILE(myf, facc);
    #pragma unroll
    for (int c = 0; c < 8; ++c) acc[c] = facc[c];  // keep post-LN f for next layer / pooling
  }

  // ================= pooling + fea2node + final LN =================
  float pc[8];
  #pragma unroll
  for (int c = 0; c < 8; ++c) {
    float s = acc[c][0] + acc[c][1] + acc[c][2] + acc[c][3];
    s += __shfl_xor(s, 16, 64);
    s += __shfl_xor(s, 32, 64);
    pc[c] = s * (1.f / 16.f);
  }
  float* ps = (float*)myQ;  // 128 floats scratch
  if (lq == 0) {
    #pragma unroll
    for (int c = 0; c < 8; ++c) ps[c * 16 + li] = pc[c];
  }
  const short* F2NT = wsb + OFF_F2N;
  float yv[2];
  #pragma unroll
  for (int half = 0; half < 2; ++half) {
    int col = half * 64 + lane;
    float dot = 0.f;
    for (int d0 = 0; d0 < 128; d0 += 8) {
      bf16x8 wv8 = *(const bf16x8*)(F2NT + col * 128 + d0);
      f32x4 p0 = *(const f32x4*)(ps + d0);
      f32x4 p1 = *(const f32x4*)(ps + d0 + 4);
      dot += p0[0] * bf2f(wv8[0]) + p0[1] * bf2f(wv8[1]) + p0[2] * bf2f(wv8[2]) + p0[3] * bf2f(wv8[3]);
      dot += p1[0] * bf2f(wv8[4]) + p1[1] * bf2f(wv8[5]) + p1[2] * bf2f(wv8[6]) + p1[3] * bf2f(wv8[7]);
    }
    yv[half] = gelu_f(dot + f2n_b[col]) + node_h[(size_t)n * 128 + col];
  }
  float s1 = yv[0] + yv[1], s2 = yv[0] * yv[0] + yv[1] * yv[1];
  #pragma unroll
  for (int m = 1; m <= 32; m <<= 1) { s1 += __shfl_xor(s1, m, 64); s2 += __shfl_xor(s2, m, 64); }
  float mean = s1 * (1.f / 128.f);
  float var = s2 * (1.f / 128.f) - mean * mean;
  float rstd = rsqrtf(var + 1e-5f);
  #pragma unroll
  for (int half = 0; half < 2; ++half) {
    int col = half * 64 + lane;
    out[(size_t)n * 128 + col] = (yv[half] - mean) * rstd * fin_g[col] + fin_b[col];
  }
}

extern "C" void kernel_launch(void* const* d_in, const int* in_sizes, int n_in,
                              void* d_out, int out_size, void* d_ws, size_t ws_size,
                              hipStream_t stream) {
  const float* node_h    = (const float*)d_in[0];
  const int*   src_idx   = (const int*)d_in[1];
  const float* edge_feat = (const float*)d_in[2];
  const float* t_arr     = (const float*)d_in[3];
  const float* t_now     = (const float*)d_in[4];
  const float* edge_fc_w = (const float*)d_in[5];
  const float* edge_fc_b = (const float*)d_in[6];
  const float* basis_frq = (const float*)d_in[7];
  const float* phase     = (const float*)d_in[8];
  const float* wq        = (const float*)d_in[9];
  const float* wk        = (const float*)d_in[10];
  const float* wv        = (const float*)d_in[11];
  const float* attn_fc_w = (const float*)d_in[12];
  const float* attn_fc_b = (const float*)d_in[13];
  const float* attn_ln_g = (const float*)d_in[14];
  const float* attn_ln_b = (const float*)d_in[15];
  const float* ffn_w1    = (const float*)d_in[16];
  const float* ffn_b1    = (const float*)d_in[17];
  const float* ffn_w2    = (const float*)d_in[18];
  const float* ffn_b2    = (const float*)d_in[19];
  const float* ffn_ln_g  = (const float*)d_in[20];
  const float* ffn_ln_b  = (const float*)d_in[21];
  const float* f2n_w     = (const float*)d_in[22];
  const float* f2n_b     = (const float*)d_in[23];
  const float* fin_g     = (const float*)d_in[24];
  const float* fin_b     = (const float*)d_in[25];
  short* wsb = (short*)d_ws;

  prep_kernel<<<(TOTAL_W + 255) / 256, 256, 0, stream>>>(
      edge_fc_w, wq, wk, wv, attn_fc_w, ffn_w1, ffn_w2, f2n_w, wsb);
  fused_kernel<<<NN / 4, 256, 0, stream>>>(
      node_h, src_idx, edge_feat, t_arr, t_now, edge_fc_b, basis_frq, phase,
      attn_fc_b, attn_ln_g, attn_ln_b, ffn_b1, ffn_b2, ffn_ln_g, ffn_ln_b,
      f2n_b, fin_g, fin_b, wsb, (float*)d_out);
}